// Round 16
// baseline (255.646 us; speedup 1.0000x reference)
//
#include <hip/hip_runtime.h>
#include <math.h>

#define NSMP 48
#define FSTR 72    // feat row stride in f16 (72 data, no pad; 144B rows, 2-way banks = free)
#define HSTR 72    // hid row stride in f16 (64 + 8 pad; 144B, 16B-aligned)
#define WAVES 4

typedef _Float16 f16;
typedef _Float16 half8 __attribute__((ext_vector_type(8)));
typedef _Float16 half4 __attribute__((ext_vector_type(4)));
typedef _Float16 h2    __attribute__((ext_vector_type(2)));
typedef float    f32x4 __attribute__((ext_vector_type(4)));

__device__ __forceinline__ float sigmoid_f(float x){
    return __builtin_amdgcn_rcpf(1.0f + __expf(-x));
}
// fast f16 gelu: Phi-table indexed by top-10 bits of the f16 value.
// Table stored at stride 4B (even f16 slots) so adjacent bins hit different LDS banks.
__device__ __forceinline__ h2 gelu16x2(h2 x, const f16* __restrict__ lutB){
    const uint32_t w = __builtin_bit_cast(uint32_t, x);
    h2 m = { lutB[(w>>5) & 0x7FE], lutB[(w>>21) & 0x7FE] };
    return x * m;
}
__device__ __forceinline__ f16 gelu16_1(f16 x, const f16* __restrict__ lutB){
    const uint16_t w = __builtin_bit_cast(uint16_t, x);
    return x * lutB[((uint32_t)w>>5) & 0x7FE];
}
// wave-synchronous LDS fence (per-wave LDS regions)
#define LDS_FENCE() asm volatile("s_waitcnt lgkmcnt(0)" ::: "memory")

template<bool TR>
__global__ __launch_bounds__(WAVES*64, 4)
void render_kernel(const float* __restrict__ rays_o,
                   const float* __restrict__ rays_d,
                   const f16*   __restrict__ mats16,  // TR: [ib][pix][32] f16
                   const f16*   __restrict__ vecs16,  // TR: [ib][r][32] f16
                   const float* __restrict__ matsf,   // !TR: original f32 layout
                   const float* __restrict__ vecsf,
                   const f16*   __restrict__ wT,      // [64][96] f16, 0-pad k>=72
                   const float* __restrict__ g_bmat,
                   const f16*   __restrict__ w1T,     // [64][64] f16
                   const float* __restrict__ g_b1,
                   const float* __restrict__ g_w1,    // f32 w1 (PE rows; !TR fallback only)
                   const float* __restrict__ pe_buf,  // TR: [NR][64] precomputed PE fold
                   const f16*   __restrict__ w2T16,   // [16][64] f16: rows 0..2 = w2^T, rest 0
                   const float* __restrict__ g_b2,
                   float* __restrict__ out, int B, int R)
{
    __shared__ f16 s_buf[WAVES][NSMP*FSTR];   // 27648 B (feat, then hid, then gelu(h2))
    __shared__ f16 s_lutB[2048];              // 4096 B (Phi table, 4B stride) -> 31744 B

    const int tid  = threadIdx.x;

    // build Phi LUT (block-shared), BEFORE any wave can exit
    for (int i = tid; i < 1024; i += WAVES*64){
        const unsigned short bits = (unsigned short)((i<<6) | 0x20);  // bin midpoint
        const f16 xh = __builtin_bit_cast(f16, bits);
        float m;
        if (((i>>4)&0x1F) == 31) m = (i & 0x200) ? 0.0f : 1.0f;       // inf/nan bins
        else {
            const float x = (float)xh;
            m = 0.5f*(1.0f + erff(x*0.70710678118654752f));           // Phi(x)
        }
        s_lutB[2*i] = (f16)m;
    }
    __syncthreads();
    const f16* lutB = s_lutB;

    const int wv   = tid >> 6;
    const int lane = tid & 63;
    const int NR   = B*R;
    const int ray  = blockIdx.x*WAVES + wv;
    if (ray >= NR) return;                    // wave-uniform exit (after barrier)
    const int b = ray / R;

    f16* gF = s_buf[wv];
    f16* gH = s_buf[wv];                      // overlay

    const float ox=rays_o[ray*3+0], oy=rays_o[ray*3+1], oz=rays_o[ray*3+2];
    const float dx=rays_d[ray*3+0], dy=rays_d[ray*3+1], dz=rays_d[ray*3+2];

    // ================= Phase 1: gather (lane = sample) =================
    const int  s      = lane;
    const bool active = (s < NSMP);
    const int  sc     = active ? s : (NSMP-1);
    const float mid   = ((float)s  + 0.5f) * 0.03125f;
    const float midc  = ((float)sc + 0.5f) * 0.03125f;

    const float x0c = 1.25f*(ox + dx*midc);
    const float x1c = 1.25f*(oy + dy*midc);
    const float x2c = 1.25f*(oz + dz*midc);

    float sigma = 0.0f;

    #pragma unroll 1
    for (int i=0;i<3;i++){
        // MAT_MODE = {{0,1},{2,0},{1,2}}, VEC_MODE = {2,1,0}
        const float cx = (i==0)? x0c : (i==1)? x2c : x1c;
        const float cy = (i==0)? x1c : (i==1)? x0c : x2c;
        const float cv = (i==0)? x2c : (i==1)? x1c : x0c;

        const float px = (cx+1.0f)*23.5f;
        const float py = (cy+1.0f)*23.5f;
        const float fx0 = floorf(px), fy0 = floorf(py);
        const float wx = px-fx0, wy = py-fy0;
        const int ix0 = (int)fx0, iy0 = (int)fy0;

        int   toff[4];
        float tw[4];
        #pragma unroll
        for (int t=0;t<4;t++){
            const int xx = ix0 + (t&1);
            const int yy = iy0 + (t>>1);
            const bool inb = (xx>=0)&&(xx<48)&&(yy>=0)&&(yy<48);
            const int xcl = min(max(xx,0),47);
            const int ycl = min(max(yy,0),47);
            toff[t] = ycl*48+xcl;
            const float wxx = (t&1)? wx : 1.0f-wx;
            const float wyy = (t>>1)? wy : 1.0f-wy;
            tw[t] = inb ? wxx*wyy : 0.0f;
        }

        const float pv = (cv+1.0f)*23.5f;
        const float fp0 = floorf(pv);
        const float wvv = pv-fp0;
        const int ip0 = (int)fp0;
        int voff[2]; float vw[2];
        #pragma unroll
        for (int t=0;t<2;t++){
            const int pp = ip0+t;
            const bool inb = (pp>=0)&&(pp<48);
            voff[t] = min(max(pp,0),47);
            vw[t] = inb ? ((t)? wvv : 1.0f-wvv) : 0.0f;
        }

        if (TR){
            const f16* pb = mats16 + ((size_t)(i*B+b))*(2304u*32u);
            const f16* vb = vecs16 + ((size_t)(i*B+b))*(48u*32u);
            const half8* t0 = (const half8*)(pb + toff[0]*32);
            const half8* t1 = (const half8*)(pb + toff[1]*32);
            const half8* t2 = (const half8*)(pb + toff[2]*32);
            const half8* t3 = (const half8*)(pb + toff[3]*32);
            const half8* v0 = (const half8*)(vb + voff[0]*32);
            const half8* v1 = (const half8*)(vb + voff[1]*32);

            const h2 tw0h = {(f16)tw[0],(f16)tw[0]};
            const h2 tw1h = {(f16)tw[1],(f16)tw[1]};
            const h2 tw2h = {(f16)tw[2],(f16)tw[2]};
            const h2 tw3h = {(f16)tw[3],(f16)tw[3]};
            const h2 vw0h = {(f16)vw[0],(f16)vw[0]};
            const h2 vw1h = {(f16)vw[1],(f16)vw[1]};

            // 8 channels per iter, packed-f16 blend + f16-LUT gelu
            #pragma unroll 2
            for (int c4=0;c4<4;c4++){
                const half8 a0=t0[c4], a1=t1[c4], a2=t2[c4], a3=t3[c4];
                const half8 q0=v0[c4], q1=v1[c4];
                h2 gg[4];
                #pragma unroll
                for (int j=0;j<4;j++){
                    const h2 a0j = {a0[2*j], a0[2*j+1]};
                    const h2 a1j = {a1[2*j], a1[2*j+1]};
                    const h2 a2j = {a2[2*j], a2[2*j+1]};
                    const h2 a3j = {a3[2*j], a3[2*j+1]};
                    const h2 q0j = {q0[2*j], q0[2*j+1]};
                    const h2 q1j = {q1[2*j], q1[2*j+1]};
                    h2 pf = a0j*tw0h; pf += a1j*tw1h; pf += a2j*tw2h; pf += a3j*tw3h;
                    h2 vf = q0j*vw0h; vf += q1j*vw1h;
                    const h2 fj = pf*vf;
                    if (c4==0){
                        sigma += (float)fj[0] + (float)fj[1];
                    } else {
                        gg[j] = gelu16x2(fj, lutB);
                    }
                }
                if (c4>0 && active){
                    half8 hv = {gg[0][0],gg[0][1],gg[1][0],gg[1][1],
                                gg[2][0],gg[2][1],gg[3][0],gg[3][1]};
                    *(half8*)(gF + s*FSTR + i*24 + c4*8 - 8) = hv;
                }
            }
        } else {
            const float* pb = matsf + ((size_t)(i*B+b))*(32u*2304u);
            const float* vb = vecsf + ((size_t)(i*B+b))*(32u*48u);
            #pragma unroll 2
            for (int c=0;c<32;c++){
                const float* fc = pb + c*2304;
                const float pf = tw[0]*fc[toff[0]] + tw[1]*fc[toff[1]]
                               + tw[2]*fc[toff[2]] + tw[3]*fc[toff[3]];
                const float* vc = vb + c*48;
                const float vf = vw[0]*vc[voff[0]] + vw[1]*vc[voff[1]];
                const float r = pf*vf;
                if (c < 8) sigma += r;
                else if (active) gF[s*FSTR + i*24 + c - 8] = gelu16_1((f16)r, lutB);
            }
        }
    }

    const int q  = lane >> 4;   // quad
    const int cl = lane & 15;   // col index within tile

    // ======== Phase 2: layer-1 GEMM  hid^T(64x48) = wT(64x96) @ feat^T(96x48) ========
    f32x4 acc[4][3];
    #pragma unroll
    for (int mt=0;mt<4;mt++){
        const float4 bmv = *(const float4*)(g_bmat + mt*16 + q*4);
        #pragma unroll
        for (int nt=0;nt<3;nt++){
            acc[mt][nt][0]=bmv.x; acc[mt][nt][1]=bmv.y; acc[mt][nt][2]=bmv.z; acc[mt][nt][3]=bmv.w;
        }
    }

    LDS_FENCE();   // feat writes visible to whole wave

    #pragma unroll 1
    for (int ks=0; ks<2; ks++){
        half8 bf[3];
        #pragma unroll
        for (int nt=0;nt<3;nt++)
            bf[nt] = *(const half8*)(gF + (nt*16+cl)*FSTR + ks*32 + q*8);
        #pragma unroll
        for (int mt=0;mt<4;mt++){
            const half8 af = *(const half8*)(wT + (mt*16+cl)*96 + ks*32 + q*8);
            #pragma unroll
            for (int nt=0;nt<3;nt++)
                acc[mt][nt] = __builtin_amdgcn_mfma_f32_16x16x32_f16(af, bf[nt], acc[mt][nt], 0,0,0);
        }
    }
    {   // ks=2: only q==0 holds real B data (k=64..71); wT rows k>=72 are zero-padded.
        half8 bf[3] = {{0,0,0,0,0,0,0,0},{0,0,0,0,0,0,0,0},{0,0,0,0,0,0,0,0}};
        if (q == 0){
            #pragma unroll
            for (int nt=0;nt<3;nt++)
                bf[nt] = *(const half8*)(gF + (nt*16+cl)*FSTR + 64);
        }
        #pragma unroll
        for (int mt=0;mt<4;mt++){
            const half8 af = *(const half8*)(wT + (mt*16+cl)*96 + 64 + q*8);
            #pragma unroll
            for (int nt=0;nt<3;nt++)
                acc[mt][nt] = __builtin_amdgcn_mfma_f32_16x16x32_f16(af, bf[nt], acc[mt][nt], 0,0,0);
        }
    }

    // gelu (f16 LUT, via pack-cvt) + store hid^T into the SAME LDS region
    LDS_FENCE();   // all feat reads drained before overwrite
    #pragma unroll
    for (int mt=0;mt<4;mt++){
        #pragma unroll
        for (int nt=0;nt<3;nt++){
            const h2 p01 = __builtin_bit_cast(h2,
                __builtin_amdgcn_cvt_pkrtz(acc[mt][nt][0], acc[mt][nt][1]));
            const h2 p23 = __builtin_bit_cast(h2,
                __builtin_amdgcn_cvt_pkrtz(acc[mt][nt][2], acc[mt][nt][3]));
            const h2 g01 = gelu16x2(p01, lutB);
            const h2 g23 = gelu16x2(p23, lutB);
            half4 hv = {g01[0], g01[1], g23[0], g23[1]};
            *(half4*)(gH + (nt*16+cl)*HSTR + mt*16 + q*4) = hv;
        }
    }

    // ================= Phase 3: PE fold =================
    float pe;
    if (TR){
        pe = pe_buf[(size_t)ray*64 + lane];           // precomputed in prep
    } else {
        pe = g_b1[lane];
        const float inv_n = rsqrtf(dx*dx+dy*dy+dz*dz);
        const float vd0=dx*inv_n, vd1=dy*inv_n, vd2=dz*inv_n;
        pe += vd0*g_w1[64*64+lane] + vd1*g_w1[65*64+lane] + vd2*g_w1[66*64+lane];
        #pragma unroll 1
        for (int fq=0; fq<4; fq++){
            const float fs = (float)(1<<fq);
            float s0,c0,s1,c1,s2,c2;
            __sincosf(vd0*fs, &s0, &c0);
            __sincosf(vd1*fs, &s1, &c1);
            __sincosf(vd2*fs, &s2, &c2);
            pe += s0*g_w1[(67+fq*3+0)*64+lane];
            pe += s1*g_w1[(67+fq*3+1)*64+lane];
            pe += s2*g_w1[(67+fq*3+2)*64+lane];
            pe += c0*g_w1[(79+fq*3+0)*64+lane];
            pe += c1*g_w1[(79+fq*3+1)*64+lane];
            pe += c2*g_w1[(79+fq*3+2)*64+lane];
        }
    }

    // ======== Phase 4: layer-2 GEMM  h2^T(64x48) = w1T(64x64) @ hid^T(64x48) ========
    f32x4 acc2[4][3];
    #pragma unroll
    for (int mt=0;mt<4;mt++){
        const float p0 = __shfl(pe, mt*16+q*4+0, 64);
        const float p1 = __shfl(pe, mt*16+q*4+1, 64);
        const float p2 = __shfl(pe, mt*16+q*4+2, 64);
        const float p3 = __shfl(pe, mt*16+q*4+3, 64);
        #pragma unroll
        for (int nt=0;nt<3;nt++){
            acc2[mt][nt][0]=p0; acc2[mt][nt][1]=p1; acc2[mt][nt][2]=p2; acc2[mt][nt][3]=p3;
        }
    }

    LDS_FENCE();   // hid writes visible

    #pragma unroll 1
    for (int ks=0; ks<2; ks++){
        half8 bf[3];
        #pragma unroll
        for (int nt=0;nt<3;nt++)
            bf[nt] = *(const half8*)(gH + (nt*16+cl)*HSTR + ks*32 + q*8);
        #pragma unroll
        for (int mt=0;mt<4;mt++){
            const half8 af = *(const half8*)(w1T + (mt*16+cl)*64 + ks*32 + q*8);
            #pragma unroll
            for (int nt=0;nt<3;nt++)
                acc2[mt][nt] = __builtin_amdgcn_mfma_f32_16x16x32_f16(af, bf[nt], acc2[mt][nt], 0,0,0);
        }
    }

    // ======== Phase 5: layer 3 via MFMA  rgb^T(16x48) = w2T16(16x64) @ gelu(h2)^T(64x48) ========
    LDS_FENCE();   // phase-4 hid reads drained before overwrite
    #pragma unroll
    for (int mt=0;mt<4;mt++){
        #pragma unroll
        for (int nt=0;nt<3;nt++){
            const h2 p01 = __builtin_bit_cast(h2,
                __builtin_amdgcn_cvt_pkrtz(acc2[mt][nt][0], acc2[mt][nt][1]));
            const h2 p23 = __builtin_bit_cast(h2,
                __builtin_amdgcn_cvt_pkrtz(acc2[mt][nt][2], acc2[mt][nt][3]));
            const h2 g01 = gelu16x2(p01, lutB);
            const h2 g23 = gelu16x2(p23, lutB);
            half4 hv = {g01[0], g01[1], g23[0], g23[1]};
            *(half4*)(gH + (nt*16+cl)*HSTR + mt*16 + q*4) = hv;
        }
    }

    const float b20=g_b2[0], b21=g_b2[1], b22=g_b2[2];
    f32x4 acc3[3];
    #pragma unroll
    for (int nt=0;nt<3;nt++){
        acc3[nt][0] = (q==0)? b20 : 0.0f;
        acc3[nt][1] = (q==0)? b21 : 0.0f;
        acc3[nt][2] = (q==0)? b22 : 0.0f;
        acc3[nt][3] = 0.0f;
    }

    LDS_FENCE();   // gelu(h2) visible

    #pragma unroll 1
    for (int ks=0; ks<2; ks++){
        const half8 af = *(const half8*)(w2T16 + cl*64 + ks*32 + q*8);
        #pragma unroll
        for (int nt=0;nt<3;nt++){
            const half8 bf = *(const half8*)(gH + (nt*16+cl)*HSTR + ks*32 + q*8);
            acc3[nt] = __builtin_amdgcn_mfma_f32_16x16x32_f16(af, bf, acc3[nt], 0,0,0);
        }
    }

    // redistribute: lane L's sample rgb sits in lane (L&15) of tile (L>>4), rows 0..2
    float rgb0, rgb1, rgb2;
    {
        float t[3];
        #pragma unroll
        for (int r=0;r<3;r++){
            const float u0 = __shfl(acc3[0][r], cl, 64);
            const float u1 = __shfl(acc3[1][r], cl, 64);
            const float u2 = __shfl(acc3[2][r], cl, 64);
            t[r] = (q==0)? u0 : (q==1)? u1 : u2;
        }
        rgb0 = sigmoid_f(t[0]);
        rgb1 = sigmoid_f(t[1]);
        rgb2 = sigmoid_f(t[2]);
    }

    // ======== Phase 6: volume integration (lane = sample) ========
    const float sg    = fmaxf(sigma, 0.0f);
    const float alpha = active ? (1.0f - __expf(-sg*0.03125f)) : 0.0f;
    float v = active ? (1.0f - alpha + 1e-10f) : 1.0f;
    #pragma unroll
    for (int off=1; off<64; off<<=1){
        const float up = __shfl_up(v, off, 64);
        if (lane >= off) v *= up;
    }
    float T = __shfl_up(v, 1, 64);
    if (lane==0) T = 1.0f;
    const float w = alpha*T;

    if (active) out[(size_t)NR*4 + (size_t)ray*NSMP + s] = w;

    float A0=w*rgb0, A1=w*rgb1, A2=w*rgb2, AD=w*mid;
    #pragma unroll
    for (int off=32; off>0; off>>=1){
        A0 += __shfl_down(A0, off, 64);
        A1 += __shfl_down(A1, off, 64);
        A2 += __shfl_down(A2, off, 64);
        AD += __shfl_down(AD, off, 64);
    }
    if (lane==0){
        out[(size_t)ray*3+0]=A0;
        out[(size_t)ray*3+1]=A1;
        out[(size_t)ray*3+2]=A2;
        out[(size_t)NR*3 + (size_t)ray]=AD;
    }
}

// One fused prep kernel:
//  blocks [0, tileN)                   : LDS-tiled mats transpose f32 -> f16 channel-last
//  blocks [tileN, tileN+prepN)         : vec transpose + weight prep (linear index)
//  blocks [tileN+prepN, +peN)          : PE fold precompute -> pe_buf[NR][64]
__global__ __launch_bounds__(256)
void fused_prep(const float* __restrict__ mats, const float* __restrict__ vecs,
                const float* __restrict__ w_mat, const float* __restrict__ w1,
                const float* __restrict__ w2,
                const float* __restrict__ rays_d, const float* __restrict__ b1,
                f16* __restrict__ tm, f16* __restrict__ tv,
                f16* __restrict__ wT, f16* __restrict__ w1T, f16* __restrict__ w2T16,
                float* __restrict__ pe_buf,
                int tileN, int prepN, int vecsz, int NR){
    __shared__ float tl[32][33];
    const int bid = blockIdx.x;
    if (bid < tileN){
        const int ib   = bid / 72;
        const int pix0 = (bid % 72) * 32;
        const int tx = threadIdx.x & 31;
        const int ty = threadIdx.x >> 5;      // 0..7
        const float* src = mats + (size_t)ib*32*2304;
        #pragma unroll
        for (int t=0;t<4;t++){
            const int c = ty + t*8;
            tl[c][tx] = src[(size_t)c*2304 + pix0 + tx];
        }
        __syncthreads();
        f16* dst = tm + (size_t)ib*2304*32;
        #pragma unroll
        for (int t=0;t<4;t++){
            const int p = ty + t*8;
            dst[(size_t)(pix0+p)*32 + tx] = (f16)tl[tx][p];
        }
    } else if (bid < tileN + prepN){
        const int idx = (bid - tileN)*256 + threadIdx.x;
        if (idx < vecsz){
            const int r  = idx % 48;
            const int c  = (idx / 48) & 31;
            const int ib = idx / (48*32);
            tv[((size_t)ib*48+r)*32 + c] = (f16)vecs[idx];
        } else if (idx < vecsz + 64*96){
            const int i1 = idx - vecsz;
            const int n = i1 / 96, k = i1 % 96;
            wT[i1] = (k < 72) ? (f16)w_mat[k*64+n] : (f16)0.0f;
        } else if (idx < vecsz + 64*96 + 64*64){
            const int i2 = idx - vecsz - 64*96;
            const int n = i2 / 64, k = i2 % 64;
            w1T[i2] = (f16)w1[k*64+n];
        } else if (idx < vecsz + 64*96 + 64*64 + 16*64){
            const int i3 = idx - vecsz - 64*96 - 64*64;
            const int n = i3 / 64, k = i3 % 64;
            w2T16[i3] = (n < 3) ? (f16)w2[k*3+n] : (f16)0.0f;
        }
    } else {
        // PE fold: 4 rays per block, lane = hidden unit j
        const int ray  = (bid - tileN - prepN)*4 + (threadIdx.x >> 6);
        const int lane = threadIdx.x & 63;
        if (ray < NR){
            const float dx=rays_d[ray*3+0], dy=rays_d[ray*3+1], dz=rays_d[ray*3+2];
            float pe = b1[lane];
            const float inv_n = rsqrtf(dx*dx+dy*dy+dz*dz);
            const float vd0=dx*inv_n, vd1=dy*inv_n, vd2=dz*inv_n;
            pe += vd0*w1[64*64+lane] + vd1*w1[65*64+lane] + vd2*w1[66*64+lane];
            #pragma unroll 1
            for (int fq=0; fq<4; fq++){
                const float fs = (float)(1<<fq);
                float s0,c0,s1,c1,s2,c2;
                __sincosf(vd0*fs, &s0, &c0);
                __sincosf(vd1*fs, &s1, &c1);
                __sincosf(vd2*fs, &s2, &c2);
                pe += s0*w1[(67+fq*3+0)*64+lane];
                pe += s1*w1[(67+fq*3+1)*64+lane];
                pe += s2*w1[(67+fq*3+2)*64+lane];
                pe += c0*w1[(79+fq*3+0)*64+lane];
                pe += c1*w1[(79+fq*3+1)*64+lane];
                pe += c2*w1[(79+fq*3+2)*64+lane];
            }
            pe_buf[(size_t)ray*64 + lane] = pe;
        }
    }
}

extern "C" void kernel_launch(void* const* d_in, const int* in_sizes, int n_in,
                              void* d_out, int out_size, void* d_ws, size_t ws_size,
                              hipStream_t stream) {
    const float* rays_o  = (const float*)d_in[0];
    const float* rays_d  = (const float*)d_in[1];
    const float* matrixs = (const float*)d_in[2];
    const float* vectors = (const float*)d_in[3];
    const float* w_mat   = (const float*)d_in[4];
    const float* b_mat   = (const float*)d_in[5];
    const float* w1      = (const float*)d_in[6];
    const float* b1      = (const float*)d_in[7];
    const float* w2      = (const float*)d_in[8];
    const float* b2      = (const float*)d_in[9];
    float* out = (float*)d_out;

    const int B = in_sizes[2] / (3*32*48*48);
    const int R = (in_sizes[0]/3) / B;
    const int NR = B*R;

    const int matsz = 3*B*32*2304;
    const int vecsz = 3*B*32*48;
    const int wtot  = 64*96 + 64*64 + 16*64;
    const size_t need_full = ((size_t)matsz + (size_t)vecsz + (size_t)wtot)*sizeof(f16)
                           + (size_t)NR*64*sizeof(float);
    const size_t need_w    = (size_t)wtot*sizeof(f16);

    const int nblk = (NR + WAVES-1)/WAVES;
    const int nthr = WAVES*64;

    if (ws_size >= need_full){
        f16* tm    = (f16*)d_ws;
        f16* tv    = tm + matsz;
        f16* wT    = tv + vecsz;
        f16* w1T   = wT + 64*96;
        f16* w2T16 = w1T + 64*64;
        float* pe_buf = (float*)(w2T16 + 16*64);
        const int tileN = 72*3*B;
        const int smalln = vecsz + wtot;
        const int prepN  = (smalln + 255)/256;
        const int peN    = (NR + 3)/4;
        fused_prep<<<tileN + prepN + peN, 256, 0, stream>>>(matrixs, vectors, w_mat, w1, w2,
                    rays_d, b1, tm, tv, wT, w1T, w2T16, pe_buf, tileN, prepN, vecsz, NR);
        render_kernel<true><<<nblk, nthr, 0, stream>>>(rays_o, rays_d, tm, tv,
            nullptr, nullptr, wT, b_mat, w1T, b1, w1, pe_buf, w2T16, b2, out, B, R);
    } else if (ws_size >= need_w){
        f16* wT    = (f16*)d_ws;
        f16* w1T   = wT + 64*96;
        f16* w2T16 = w1T + 64*64;
        const int prepN = (wtot + 255)/256;
        fused_prep<<<prepN, 256, 0, stream>>>(nullptr, nullptr, w_mat, w1, w2,
                    nullptr, nullptr, nullptr, nullptr, wT, w1T, w2T16, nullptr, 0, prepN, 0, 0);
        render_kernel<false><<<nblk, nthr, 0, stream>>>(rays_o, rays_d,
            nullptr, nullptr, matrixs, vectors, wT, b_mat, w1T, b1, w1, nullptr, w2T16, b2, out, B, R);
    }
}